// Round 1
// baseline (3236.714 us; speedup 1.0000x reference)
//
#include <hip/hip_runtime.h>
#include <math.h>

// Problem constants (from setup_inputs)
#define BL 192      // b*l = 16*12
#define NREAL 325   // real sequence length
#define NPAD 352    // padded length (multiple of 2*bucket_size=32)
#define DM 256      // d_feat
#define DPOS 64     // d_pos
#define DIN 320     // d_feat + d_pos
#define NHEADS 8
#define EDIM 32     // DM / NHEADS
#define NHASH 4
#define BS 16       // bucket_size
#define NBUCK 22    // NPAD / BS
#define NCHUNK 88   // NHASH * NBUCK
#define BHTOT 1536  // BL * NHEADS
#define RROT 11     // n_buckets // 2
#define W2COLS 352  // NHEADS * NHASH * RROT
#define RTM 8       // row tile for rot_bucket kernel

// ---------------------------------------------------------------------------
// Fused: h = [x,ste]@w_proj + b_proj (pad rows exactly 0), then
// qk = h@w_qk, v = h@w_v, per-head layout [bh][n][e].  fp64 accumulation,
// fp32 storage (smooth path — differences are sub-ulp in the bf16 compare).
__global__ __launch_bounds__(256) void projqkv_kernel(
    const float* __restrict__ x, const float* __restrict__ ste,
    const float* __restrict__ wproj, const float* __restrict__ bproj,
    const float* __restrict__ wqk, const float* __restrict__ wv,
    float* __restrict__ qk, float* __restrict__ v) {
  int tile = blockIdx.x, bl = blockIdx.y;
  int d = threadIdx.x;
  __shared__ float As[16][DIN];  // 20 KB
  __shared__ float Hs[16][DM];   // 16 KB
  int n0 = tile * 16;
  for (int idx = threadIdx.x; idx < 16 * DIN; idx += 256) {
    int m = idx / DIN, k = idx - m * DIN;
    int n = n0 + m;
    float val = 0.f;
    if (n < NREAL)
      val = (k < DM) ? x[((size_t)(bl * NREAL + n)) * DM + k]
                     : ste[((size_t)(bl * NREAL + n)) * DPOS + (k - DM)];
    As[m][k] = val;
  }
  __syncthreads();
  {
    double acc[16];
#pragma unroll
    for (int m = 0; m < 16; ++m) acc[m] = 0.0;
    for (int k = 0; k < DIN; ++k) {
      double b = (double)wproj[k * DM + d];
#pragma unroll
      for (int m = 0; m < 16; ++m) acc[m] += (double)As[m][k] * b;
    }
    double bb = (double)bproj[d];
    for (int m = 0; m < 16; ++m) {
      int n = n0 + m;
      Hs[m][d] = (n < NREAL) ? (float)(acc[m] + bb) : 0.f;  // pad rows zero
    }
  }
  __syncthreads();
  double aq[16], av[16];
#pragma unroll
  for (int m = 0; m < 16; ++m) { aq[m] = 0.0; av[m] = 0.0; }
  for (int k = 0; k < DM; ++k) {
    double wq = (double)wqk[k * DM + d];
    double wvv = (double)wv[k * DM + d];
#pragma unroll
    for (int m = 0; m < 16; ++m) {
      double hv = (double)Hs[m][k];
      aq[m] += hv * wq;
      av[m] += hv * wvv;
    }
  }
  int head = d >> 5, e = d & 31;
  size_t bh = (size_t)(bl * NHEADS + head);
  for (int m = 0; m < 16; ++m) {
    int n = n0 + m;
    qk[(bh * NPAD + n) * EDIM + e] = (float)aq[m];
    v[(bh * NPAD + n) * EDIM + e] = (float)av[m];
  }
}

// ---------------------------------------------------------------------------
// Decision path: EXACT emulation of the np-fp32 reference chain.
//   h   = [x,ste]@w_proj + b_proj : fp32, serial-k FMA (OpenBLAS sgemm order)
//   qk  = h@w_qk                  : fp32, serial-k FMA, materialized fp32
//   rot = einsum(qk, rotations)   : fp32, serial-e, separate mul+add
//                                   (np.einsum generic loop, no contraction)
//   bucket = argmax(concat(rot,-rot)), first-max tie rule.
__global__ __launch_bounds__(384) void rot_bucket_kernel(
    const float* __restrict__ x, const float* __restrict__ ste,
    const float* __restrict__ wproj, const float* __restrict__ bproj,
    const float* __restrict__ wqk, const float* __restrict__ rotations,
    int* __restrict__ buckets) {
  int tile = blockIdx.x, bl = blockIdx.y;  // tile in [0,44)
  int tid = threadIdx.x;
  __shared__ float As[RTM][DIN];    // 10,240 B
  __shared__ float Hs[RTM][DM];     //  8,192 B
  __shared__ float Qs[RTM][DM];     //  8,192 B
  __shared__ float Rs[RTM][W2COLS]; // 11,264 B
  int n0 = tile * RTM;
  for (int idx = tid; idx < RTM * DIN; idx += 384) {
    int m = idx / DIN, k = idx - m * DIN;
    int n = n0 + m;
    float val = 0.f;
    if (n < NREAL)
      val = (k < DM) ? x[((size_t)(bl * NREAL + n)) * DM + k]
                     : ste[((size_t)(bl * NREAL + n)) * DPOS + (k - DM)];
    As[m][k] = val;
  }
  __syncthreads();
  if (tid < DM) {  // h: serial-k fp32 FMA chain, k = 0..319 ascending
    float acc[RTM];
#pragma unroll
    for (int m = 0; m < RTM; ++m) acc[m] = 0.f;
    for (int k = 0; k < DIN; ++k) {
      float b = wproj[k * DM + tid];
#pragma unroll
      for (int m = 0; m < RTM; ++m) acc[m] = fmaf(As[m][k], b, acc[m]);
    }
    float bb = bproj[tid];
    for (int m = 0; m < RTM; ++m) {
      int n = n0 + m;
      Hs[m][tid] = (n < NREAL) ? (acc[m] + bb) : 0.f;  // pad rows exactly 0
    }
  }
  __syncthreads();
  if (tid < DM) {  // qk: serial-k fp32 FMA chain, k = 0..255 ascending
    float acc[RTM];
#pragma unroll
    for (int m = 0; m < RTM; ++m) acc[m] = 0.f;
    for (int k = 0; k < DM; ++k) {
      float b = wqk[k * DM + tid];
#pragma unroll
      for (int m = 0; m < RTM; ++m) acc[m] = fmaf(Hs[m][k], b, acc[m]);
    }
    for (int m = 0; m < RTM; ++m) Qs[m][tid] = acc[m];
  }
  __syncthreads();
  if (tid < W2COLS) {  // rot: serial-e fp32, separate mul and add (no fma)
    int head = tid / 44;
    int hr = tid - head * 44;
    int hs = hr / RROT;
    int r = hr - hs * RROT;
    float acc[RTM];
#pragma unroll
    for (int m = 0; m < RTM; ++m) acc[m] = 0.f;
    {
#pragma clang fp contract(off)
      for (int e = 0; e < EDIM; ++e) {
        float rr = rotations[(e * NHASH + hs) * RROT + r];
#pragma unroll
        for (int m = 0; m < RTM; ++m) {
          float p = Qs[m][head * EDIM + e] * rr;
          acc[m] = acc[m] + p;
        }
      }
    }
    for (int m = 0; m < RTM; ++m) Rs[m][tid] = acc[m];
  }
  __syncthreads();
  if (tid < RTM * 32) {
    int m = tid >> 5;
    int rest = tid & 31;
    int head = rest >> 2;
    int hs = rest & 3;
    int cbase = head * 44 + hs * RROT;
    // argmax over concat([rot, -rot]), first-occurrence tie rule (strict >)
    float bestv = Rs[m][cbase];
    int best = 0;
    for (int r = 1; r < RROT; ++r) {
      float dv = Rs[m][cbase + r];
      if (dv > bestv) { bestv = dv; best = r; }
    }
    for (int r = 0; r < RROT; ++r) {
      float dv = -Rs[m][cbase + r];
      if (dv > bestv) { bestv = dv; best = RROT + r; }
    }
    int n = n0 + m;
    int bh = bl * NHEADS + head;
    buckets[((size_t)(bh * NHASH + hs)) * NPAD + n] = best;
  }
}

// ---------------------------------------------------------------------------
// Stable counting sort per (bh, hash): keys bucket*NPAD+n unique → exact argsort
__global__ __launch_bounds__(384) void sort_kernel(const int* __restrict__ buckets,
                                                   int* __restrict__ st) {
  int bh = blockIdx.x, hs = blockIdx.y;
  int n = threadIdx.x;
  __shared__ int buck[NPAD];
  const int* brow = buckets + ((size_t)(bh * NHASH + hs)) * NPAD;
  if (n < NPAD) buck[n] = brow[n];
  __syncthreads();
  if (n < NPAD) {
    int b = buck[n];
    int dest = 0;
    for (int m2 = 0; m2 < NPAD; ++m2) {
      int bm = buck[m2];
      dest += (int)((bm < b) | ((bm == b) & (m2 < n)));
    }
    st[((size_t)(bh * NHASH + hs)) * NPAD + dest] = n;
  }
}

// ---------------------------------------------------------------------------
// Pass 1: per chunk, fp64 dots → per-(bh,hash,pos) lse (stored fp32).
__global__ __launch_bounds__(512) void attn_lse_kernel(
    const float* __restrict__ qk, const int* __restrict__ st,
    float* __restrict__ ll) {
  int c = blockIdx.x, bh = blockIdx.y;
  int t = threadIdx.x;
  int i = t >> 5, j = t & 31;  // query i (0..15), key j (0..31)
  __shared__ float qs[16][EDIM];
  __shared__ float ks[32][EDIM + 1];
  __shared__ int qpos[16];
  __shared__ int kpos[32];
  __shared__ double rnorm[32];
  const int* strow = st + (size_t)bh * (NHASH * NPAD);
  int pc = (c + NCHUNK - 1) % NCHUNK;
  if (t < 16) {
    qpos[t] = strow[c * BS + t];
  } else if (t < 48) {
    int jj = t - 16;
    kpos[jj] = (jj < BS) ? strow[c * BS + jj] : strow[pc * BS + (jj - BS)];
  }
  __syncthreads();
  const float* qkb = qk + (size_t)bh * NPAD * EDIM;
  qs[i][j] = qkb[qpos[i] * EDIM + j];
#pragma unroll
  for (int rep = 0; rep < 2; ++rep) {
    int lin = t + rep * 512;
    int r = lin >> 5, cc = lin & 31;
    ks[r][cc] = qkb[kpos[r] * EDIM + cc];
  }
  __syncthreads();
  if (t < 32) {
    double s = 0.0;
#pragma unroll
    for (int e = 0; e < EDIM; ++e) { double kv = (double)ks[t][e]; s += kv * kv; }
    rnorm[t] = 1.0 / fmax(sqrt(s), 1e-12);
  }
  __syncthreads();
  double dot = 0.0;
#pragma unroll
  for (int e = 0; e < EDIM; ++e) dot += (double)qs[i][e] * (double)ks[j][e];
  dot *= rnorm[j] * 0.17677669529663688;  // E^-0.5
  if (qpos[i] == kpos[j]) dot = -50000.0;
  double mx = dot;
#pragma unroll
  for (int off = 16; off > 0; off >>= 1) mx = fmax(mx, __shfl_xor(mx, off, 32));
  double ex = exp(dot - mx);
  double sm = ex;
#pragma unroll
  for (int off = 16; off > 0; off >>= 1) sm += __shfl_xor(sm, off, 32);
  if (j == 0) {
    int hs = c / NBUCK;
    ll[((size_t)(bh * NHASH + hs)) * NPAD + qpos[i]] = (float)(mx + log(sm));
  }
}

// ---------------------------------------------------------------------------
// L[bh][n] = logsumexp over the 4 hash rounds' lse (fp64 math, fp32 store)
__global__ __launch_bounds__(256) void lcomb_kernel(const float* __restrict__ ll,
                                                    float* __restrict__ L) {
  int gid = blockIdx.x * 256 + threadIdx.x;
  if (gid >= BHTOT * NPAD) return;
  int n = gid % NPAD, bh = gid / NPAD;
  double l0 = (double)ll[((size_t)(bh * NHASH + 0)) * NPAD + n];
  double l1 = (double)ll[((size_t)(bh * NHASH + 1)) * NPAD + n];
  double l2 = (double)ll[((size_t)(bh * NHASH + 2)) * NPAD + n];
  double l3 = (double)ll[((size_t)(bh * NHASH + 3)) * NPAD + n];
  double m = fmax(fmax(l0, l1), fmax(l2, l3));
  double s = exp(l0 - m) + exp(l1 - m) + exp(l2 - m) + exp(l3 - m);
  L[gid] = (float)(m + log(s));
}

// ---------------------------------------------------------------------------
// Pass 2: fp64 dots, p = exp(dot - L[pos]) (hash-combine folded into the
// exponent), acc = p @ V in fp64, fp32 atomicAdd into att[bl][n][head*32+e].
__global__ __launch_bounds__(512) void attn_out_kernel(
    const float* __restrict__ qk, const float* __restrict__ v,
    const int* __restrict__ st, const float* __restrict__ L,
    float* __restrict__ att) {
  int c = blockIdx.x, bh = blockIdx.y;
  int t = threadIdx.x;
  int i = t >> 5, j = t & 31;
  __shared__ float qs[16][EDIM];
  __shared__ float ks[32][EDIM + 1];
  __shared__ float vs[32][EDIM + 1];
  __shared__ double ps[16][32];
  __shared__ int qpos[16];
  __shared__ int kpos[32];
  __shared__ double rnorm[32];
  const int* strow = st + (size_t)bh * (NHASH * NPAD);
  int pc = (c + NCHUNK - 1) % NCHUNK;
  if (t < 16) {
    qpos[t] = strow[c * BS + t];
  } else if (t < 48) {
    int jj = t - 16;
    kpos[jj] = (jj < BS) ? strow[c * BS + jj] : strow[pc * BS + (jj - BS)];
  }
  __syncthreads();
  const float* qkb = qk + (size_t)bh * NPAD * EDIM;
  const float* vb = v + (size_t)bh * NPAD * EDIM;
  qs[i][j] = qkb[qpos[i] * EDIM + j];
#pragma unroll
  for (int rep = 0; rep < 2; ++rep) {
    int lin = t + rep * 512;
    int r = lin >> 5, cc = lin & 31;
    ks[r][cc] = qkb[kpos[r] * EDIM + cc];
    vs[r][cc] = vb[kpos[r] * EDIM + cc];
  }
  __syncthreads();
  if (t < 32) {
    double s = 0.0;
#pragma unroll
    for (int e = 0; e < EDIM; ++e) { double kv = (double)ks[t][e]; s += kv * kv; }
    rnorm[t] = 1.0 / fmax(sqrt(s), 1e-12);
  }
  __syncthreads();
  double dot = 0.0;
#pragma unroll
  for (int e = 0; e < EDIM; ++e) dot += (double)qs[i][e] * (double)ks[j][e];
  dot *= rnorm[j] * 0.17677669529663688;
  if (qpos[i] == kpos[j]) dot = -50000.0;
  ps[i][j] = exp(dot - (double)L[(size_t)bh * NPAD + qpos[i]]);
  __syncthreads();
  double acc = 0.0;
#pragma unroll
  for (int jj = 0; jj < 32; ++jj) acc += ps[i][jj] * (double)vs[jj][j];
  int head = bh & 7, bl = bh >> 3;
  int qp = qpos[i];
  atomicAdd(&att[((size_t)(bl * NPAD + qp)) * DM + head * EDIM + j], (float)acc);
}

// ---------------------------------------------------------------------------
// out = att @ w_out + b_out (fp64 accumulate), first NREAL rows only
__global__ __launch_bounds__(256) void outproj_kernel(
    const float* __restrict__ att, const float* __restrict__ w,
    const float* __restrict__ bias, float* __restrict__ out) {
  int tile = blockIdx.x, bl = blockIdx.y;
  int d = threadIdx.x;
  __shared__ float As[16][DM];
  int n0 = tile * 16;
  for (int idx = threadIdx.x; idx < 16 * DM; idx += 256) {
    int m = idx >> 8, k = idx & 255;
    int n = n0 + m;
    As[m][k] = (n < NREAL) ? att[((size_t)(bl * NPAD + n)) * DM + k] : 0.f;
  }
  __syncthreads();
  double acc[16];
#pragma unroll
  for (int m = 0; m < 16; ++m) acc[m] = 0.0;
  for (int k = 0; k < DM; ++k) {
    double b = (double)w[k * DM + d];
#pragma unroll
    for (int m = 0; m < 16; ++m) acc[m] += (double)As[m][k] * b;
  }
  double bb = (double)bias[d];
  for (int m = 0; m < 16; ++m) {
    int n = n0 + m;
    if (n < NREAL) out[((size_t)(bl * NREAL + n)) * DM + d] = (float)(acc[m] + bb);
  }
}

// ---------------------------------------------------------------------------
extern "C" void kernel_launch(void* const* d_in, const int* in_sizes, int n_in,
                              void* d_out, int out_size, void* d_ws, size_t ws_size,
                              hipStream_t stream) {
  (void)in_sizes; (void)n_in; (void)out_size;
  const float* x = (const float*)d_in[0];
  const float* ste = (const float*)d_in[1];
  const float* w_proj = (const float*)d_in[2];
  const float* b_proj = (const float*)d_in[3];
  const float* w_qk = (const float*)d_in[4];
  const float* w_v = (const float*)d_in[5];
  const float* w_out = (const float*)d_in[6];
  const float* b_out = (const float*)d_in[7];
  const float* rotations = (const float*)d_in[8];
  float* out = (float*)d_out;

  // Workspace layout (~227 MB, known to fit from R2/R3):
  const size_t szh = (size_t)BL * NPAD * DM;         // 17,301,504 elements
  const size_t szst = (size_t)BHTOT * NHASH * NPAD;  // 2,162,688 elements
  const size_t szL = (size_t)BHTOT * NPAD;           // 540,672 elements
  const size_t needed = 3 * szh * 4 + 2 * szst * 4 + szL * 4;
  if (ws_size < needed) return;  // diagnosable clean failure, not a fault

  float* qk = (float*)d_ws;
  float* v = qk + szh;
  float* att = v + szh;
  int* st = (int*)(att + szh);
  int* buckets = st + szst;
  float* ll = (float*)buckets;  // alias: buckets consumed by sort first
  float* L = (float*)(buckets + szst);

  (void)hipMemsetAsync(att, 0, szh * sizeof(float), stream);
  projqkv_kernel<<<dim3(NPAD / 16, BL), dim3(256), 0, stream>>>(
      x, ste, w_proj, b_proj, w_qk, w_v, qk, v);
  rot_bucket_kernel<<<dim3(NPAD / RTM, BL), dim3(384), 0, stream>>>(
      x, ste, w_proj, b_proj, w_qk, rotations, buckets);
  sort_kernel<<<dim3(BHTOT, NHASH), dim3(384), 0, stream>>>(buckets, st);
  attn_lse_kernel<<<dim3(NCHUNK, BHTOT), dim3(512), 0, stream>>>(qk, st, ll);
  lcomb_kernel<<<dim3((BHTOT * NPAD + 255) / 256), dim3(256), 0, stream>>>(ll, L);
  attn_out_kernel<<<dim3(NCHUNK, BHTOT), dim3(512), 0, stream>>>(qk, v, st, L, att);
  outproj_kernel<<<dim3(21, BL), dim3(256), 0, stream>>>(att, w_out, b_out, out);
}

// Round 2
// 2598.163 us; speedup vs baseline: 1.2458x; 1.2458x over previous
//
#include <hip/hip_runtime.h>
#include <math.h>

// Problem constants (from setup_inputs)
#define BL 192      // b*l = 16*12
#define NREAL 325   // real sequence length
#define NPAD 352    // padded length (multiple of 2*bucket_size=32)
#define DM 256      // d_feat
#define DPOS 64     // d_pos
#define DIN 320     // d_feat + d_pos
#define NHEADS 8
#define EDIM 32     // DM / NHEADS
#define NHASH 4
#define BS 16       // bucket_size
#define NBUCK 22    // NPAD / BS
#define NCHUNK 88   // NHASH * NBUCK
#define BHTOT 1536  // BL * NHEADS
#define RROT 11     // n_buckets // 2
#define W2COLS 352  // NHEADS * NHASH * RROT
#define RTM 8       // row tile for rot_bucket kernel

// ---------------------------------------------------------------------------
// Fused decision + smooth-input path.  EXACT emulation of the np-fp32
// reference chain (serial-k fp32 FMA, ascending k — OpenBLAS sgemm order):
//   h   = [x,ste]@w_proj + b_proj   (pad rows exactly 0)
//   qk  = h@w_qk                    → written to global (bit-exact fp32)
//   v   = h@w_v                     → written to global (bit-exact fp32)
//   rot = einsum(qk, rotations)     fp32, separate mul+add (no fma)
//   bucket = argmax(concat(rot,-rot)), first-max tie rule.
// qk/v feed the attention kernels directly — they equal the reference's own
// fp32 values bit-exactly, so the smooth path needs no fp64 GEMM at all.
__global__ __launch_bounds__(384) void rot_bucket_kernel(
    const float* __restrict__ x, const float* __restrict__ ste,
    const float* __restrict__ wproj, const float* __restrict__ bproj,
    const float* __restrict__ wqk, const float* __restrict__ wv,
    const float* __restrict__ rotations,
    int* __restrict__ buckets, float* __restrict__ qk_out,
    float* __restrict__ v_out) {
  int tile = blockIdx.x, bl = blockIdx.y;  // tile in [0,44)
  int tid = threadIdx.x;
  __shared__ float As[RTM][DIN];    // 10,240 B
  __shared__ float Hs[RTM][DM];     //  8,192 B
  __shared__ float Qs[RTM][DM];     //  8,192 B
  __shared__ float Rs[RTM][W2COLS]; // 11,264 B
  int n0 = tile * RTM;
  for (int idx = tid; idx < RTM * DIN; idx += 384) {
    int m = idx / DIN, k = idx - m * DIN;
    int n = n0 + m;
    float val = 0.f;
    if (n < NREAL)
      val = (k < DM) ? x[((size_t)(bl * NREAL + n)) * DM + k]
                     : ste[((size_t)(bl * NREAL + n)) * DPOS + (k - DM)];
    As[m][k] = val;
  }
  __syncthreads();
  if (tid < DM) {  // h: serial-k fp32 FMA chain, k = 0..319 ascending
    float acc[RTM];
#pragma unroll
    for (int m = 0; m < RTM; ++m) acc[m] = 0.f;
    for (int k = 0; k < DIN; ++k) {
      float b = wproj[k * DM + tid];
#pragma unroll
      for (int m = 0; m < RTM; ++m) acc[m] = fmaf(As[m][k], b, acc[m]);
    }
    float bb = bproj[tid];
    for (int m = 0; m < RTM; ++m) {
      int n = n0 + m;
      Hs[m][tid] = (n < NREAL) ? (acc[m] + bb) : 0.f;  // pad rows exactly 0
    }
  }
  __syncthreads();
  if (tid < DM) {
    int head = tid >> 5, e = tid & 31;
    size_t bh = (size_t)(bl * NHEADS + head);
    {  // qk: serial-k fp32 FMA chain, k = 0..255 ascending
      float acc[RTM];
#pragma unroll
      for (int m = 0; m < RTM; ++m) acc[m] = 0.f;
      for (int k = 0; k < DM; ++k) {
        float b = wqk[k * DM + tid];
#pragma unroll
        for (int m = 0; m < RTM; ++m) acc[m] = fmaf(Hs[m][k], b, acc[m]);
      }
      for (int m = 0; m < RTM; ++m) {
        Qs[m][tid] = acc[m];
        int n = n0 + m;
        qk_out[(bh * NPAD + n) * EDIM + e] = acc[m];
      }
    }
    {  // v: serial-k fp32 FMA chain (smooth path; bit-exact to reference)
      float av[RTM];
#pragma unroll
      for (int m = 0; m < RTM; ++m) av[m] = 0.f;
      for (int k = 0; k < DM; ++k) {
        float b = wv[k * DM + tid];
#pragma unroll
        for (int m = 0; m < RTM; ++m) av[m] = fmaf(Hs[m][k], b, av[m]);
      }
      for (int m = 0; m < RTM; ++m) {
        int n = n0 + m;
        v_out[(bh * NPAD + n) * EDIM + e] = av[m];
      }
    }
  }
  __syncthreads();
  if (tid < W2COLS) {  // rot: serial-e fp32, separate mul and add (no fma)
    int head = tid / 44;
    int hr = tid - head * 44;
    int hs = hr / RROT;
    int r = hr - hs * RROT;
    float acc[RTM];
#pragma unroll
    for (int m = 0; m < RTM; ++m) acc[m] = 0.f;
    {
#pragma clang fp contract(off)
      for (int e = 0; e < EDIM; ++e) {
        float rr = rotations[(e * NHASH + hs) * RROT + r];
#pragma unroll
        for (int m = 0; m < RTM; ++m) {
          float p = Qs[m][head * EDIM + e] * rr;
          acc[m] = acc[m] + p;
        }
      }
    }
    for (int m = 0; m < RTM; ++m) Rs[m][tid] = acc[m];
  }
  __syncthreads();
  if (tid < RTM * 32) {
    int m = tid >> 5;
    int rest = tid & 31;
    int head = rest >> 2;
    int hs = rest & 3;
    int cbase = head * 44 + hs * RROT;
    // argmax over concat([rot, -rot]), first-occurrence tie rule (strict >)
    float bestv = Rs[m][cbase];
    int best = 0;
    for (int r = 1; r < RROT; ++r) {
      float dv = Rs[m][cbase + r];
      if (dv > bestv) { bestv = dv; best = r; }
    }
    for (int r = 0; r < RROT; ++r) {
      float dv = -Rs[m][cbase + r];
      if (dv > bestv) { bestv = dv; best = RROT + r; }
    }
    int n = n0 + m;
    int bh = bl * NHEADS + head;
    buckets[((size_t)(bh * NHASH + hs)) * NPAD + n] = best;
  }
}

// ---------------------------------------------------------------------------
// Stable counting sort per (bh, hash): keys bucket*NPAD+n unique → exact argsort
__global__ __launch_bounds__(384) void sort_kernel(const int* __restrict__ buckets,
                                                   int* __restrict__ st) {
  int bh = blockIdx.x, hs = blockIdx.y;
  int n = threadIdx.x;
  __shared__ int buck[NPAD];
  const int* brow = buckets + ((size_t)(bh * NHASH + hs)) * NPAD;
  if (n < NPAD) buck[n] = brow[n];
  __syncthreads();
  if (n < NPAD) {
    int b = buck[n];
    int dest = 0;
    for (int m2 = 0; m2 < NPAD; ++m2) {
      int bm = buck[m2];
      dest += (int)((bm < b) | ((bm == b) & (m2 < n)));
    }
    st[((size_t)(bh * NHASH + hs)) * NPAD + dest] = n;
  }
}

// ---------------------------------------------------------------------------
// Pass 1: per chunk, fp64 dots → per-(bh,hash,pos) lse (stored fp32).
__global__ __launch_bounds__(512) void attn_lse_kernel(
    const float* __restrict__ qk, const int* __restrict__ st,
    float* __restrict__ ll) {
  int c = blockIdx.x, bh = blockIdx.y;
  int t = threadIdx.x;
  int i = t >> 5, j = t & 31;  // query i (0..15), key j (0..31)
  __shared__ float qs[16][EDIM];
  __shared__ float ks[32][EDIM + 1];
  __shared__ int qpos[16];
  __shared__ int kpos[32];
  __shared__ double rnorm[32];
  const int* strow = st + (size_t)bh * (NHASH * NPAD);
  int pc = (c + NCHUNK - 1) % NCHUNK;
  if (t < 16) {
    qpos[t] = strow[c * BS + t];
  } else if (t < 48) {
    int jj = t - 16;
    kpos[jj] = (jj < BS) ? strow[c * BS + jj] : strow[pc * BS + (jj - BS)];
  }
  __syncthreads();
  const float* qkb = qk + (size_t)bh * NPAD * EDIM;
  qs[i][j] = qkb[qpos[i] * EDIM + j];
#pragma unroll
  for (int rep = 0; rep < 2; ++rep) {
    int lin = t + rep * 512;
    int r = lin >> 5, cc = lin & 31;
    ks[r][cc] = qkb[kpos[r] * EDIM + cc];
  }
  __syncthreads();
  if (t < 32) {
    double s = 0.0;
#pragma unroll
    for (int e = 0; e < EDIM; ++e) { double kv = (double)ks[t][e]; s += kv * kv; }
    rnorm[t] = 1.0 / fmax(sqrt(s), 1e-12);
  }
  __syncthreads();
  double dot = 0.0;
#pragma unroll
  for (int e = 0; e < EDIM; ++e) dot += (double)qs[i][e] * (double)ks[j][e];
  dot *= rnorm[j] * 0.17677669529663688;  // E^-0.5
  if (qpos[i] == kpos[j]) dot = -50000.0;
  double mx = dot;
#pragma unroll
  for (int off = 16; off > 0; off >>= 1) mx = fmax(mx, __shfl_xor(mx, off, 32));
  double ex = exp(dot - mx);
  double sm = ex;
#pragma unroll
  for (int off = 16; off > 0; off >>= 1) sm += __shfl_xor(sm, off, 32);
  if (j == 0) {
    int hs = c / NBUCK;
    ll[((size_t)(bh * NHASH + hs)) * NPAD + qpos[i]] = (float)(mx + log(sm));
  }
}

// ---------------------------------------------------------------------------
// L[bh][n] = logsumexp over the 4 hash rounds' lse (fp64 math, fp32 store)
__global__ __launch_bounds__(256) void lcomb_kernel(const float* __restrict__ ll,
                                                    float* __restrict__ L) {
  int gid = blockIdx.x * 256 + threadIdx.x;
  if (gid >= BHTOT * NPAD) return;
  int n = gid % NPAD, bh = gid / NPAD;
  double l0 = (double)ll[((size_t)(bh * NHASH + 0)) * NPAD + n];
  double l1 = (double)ll[((size_t)(bh * NHASH + 1)) * NPAD + n];
  double l2 = (double)ll[((size_t)(bh * NHASH + 2)) * NPAD + n];
  double l3 = (double)ll[((size_t)(bh * NHASH + 3)) * NPAD + n];
  double m = fmax(fmax(l0, l1), fmax(l2, l3));
  double s = exp(l0 - m) + exp(l1 - m) + exp(l2 - m) + exp(l3 - m);
  L[gid] = (float)(m + log(s));
}

// ---------------------------------------------------------------------------
// Pass 2: fp64 dots, p = exp(dot - L[pos]) (hash-combine folded into the
// exponent), acc = p @ V in fp64, fp32 atomicAdd into att[bl][n][head*32+e].
__global__ __launch_bounds__(512) void attn_out_kernel(
    const float* __restrict__ qk, const float* __restrict__ v,
    const int* __restrict__ st, const float* __restrict__ L,
    float* __restrict__ att) {
  int c = blockIdx.x, bh = blockIdx.y;
  int t = threadIdx.x;
  int i = t >> 5, j = t & 31;
  __shared__ float qs[16][EDIM];
  __shared__ float ks[32][EDIM + 1];
  __shared__ float vs[32][EDIM + 1];
  __shared__ double ps[16][32];
  __shared__ int qpos[16];
  __shared__ int kpos[32];
  __shared__ double rnorm[32];
  const int* strow = st + (size_t)bh * (NHASH * NPAD);
  int pc = (c + NCHUNK - 1) % NCHUNK;
  if (t < 16) {
    qpos[t] = strow[c * BS + t];
  } else if (t < 48) {
    int jj = t - 16;
    kpos[jj] = (jj < BS) ? strow[c * BS + jj] : strow[pc * BS + (jj - BS)];
  }
  __syncthreads();
  const float* qkb = qk + (size_t)bh * NPAD * EDIM;
  const float* vb = v + (size_t)bh * NPAD * EDIM;
  qs[i][j] = qkb[qpos[i] * EDIM + j];
#pragma unroll
  for (int rep = 0; rep < 2; ++rep) {
    int lin = t + rep * 512;
    int r = lin >> 5, cc = lin & 31;
    ks[r][cc] = qkb[kpos[r] * EDIM + cc];
    vs[r][cc] = vb[kpos[r] * EDIM + cc];
  }
  __syncthreads();
  if (t < 32) {
    double s = 0.0;
#pragma unroll
    for (int e = 0; e < EDIM; ++e) { double kv = (double)ks[t][e]; s += kv * kv; }
    rnorm[t] = 1.0 / fmax(sqrt(s), 1e-12);
  }
  __syncthreads();
  double dot = 0.0;
#pragma unroll
  for (int e = 0; e < EDIM; ++e) dot += (double)qs[i][e] * (double)ks[j][e];
  dot *= rnorm[j] * 0.17677669529663688;
  if (qpos[i] == kpos[j]) dot = -50000.0;
  ps[i][j] = exp(dot - (double)L[(size_t)bh * NPAD + qpos[i]]);
  __syncthreads();
  double acc = 0.0;
#pragma unroll
  for (int jj = 0; jj < 32; ++jj) acc += ps[i][jj] * (double)vs[jj][j];
  int head = bh & 7, bl = bh >> 3;
  int qp = qpos[i];
  atomicAdd(&att[((size_t)(bl * NPAD + qp)) * DM + head * EDIM + j], (float)acc);
}

// ---------------------------------------------------------------------------
// out = att @ w_out + b_out (fp64 accumulate), first NREAL rows only
__global__ __launch_bounds__(256) void outproj_kernel(
    const float* __restrict__ att, const float* __restrict__ w,
    const float* __restrict__ bias, float* __restrict__ out) {
  int tile = blockIdx.x, bl = blockIdx.y;
  int d = threadIdx.x;
  __shared__ float As[16][DM];
  int n0 = tile * 16;
  for (int idx = threadIdx.x; idx < 16 * DM; idx += 256) {
    int m = idx >> 8, k = idx & 255;
    int n = n0 + m;
    As[m][k] = (n < NREAL) ? att[((size_t)(bl * NPAD + n)) * DM + k] : 0.f;
  }
  __syncthreads();
  double acc[16];
#pragma unroll
  for (int m = 0; m < 16; ++m) acc[m] = 0.0;
  for (int k = 0; k < DM; ++k) {
    double b = (double)w[k * DM + d];
#pragma unroll
    for (int m = 0; m < 16; ++m) acc[m] += (double)As[m][k] * b;
  }
  double bb = (double)bias[d];
  for (int m = 0; m < 16; ++m) {
    int n = n0 + m;
    if (n < NREAL) out[((size_t)(bl * NREAL + n)) * DM + d] = (float)(acc[m] + bb);
  }
}

// ---------------------------------------------------------------------------
extern "C" void kernel_launch(void* const* d_in, const int* in_sizes, int n_in,
                              void* d_out, int out_size, void* d_ws, size_t ws_size,
                              hipStream_t stream) {
  (void)in_sizes; (void)n_in; (void)out_size;
  const float* x = (const float*)d_in[0];
  const float* ste = (const float*)d_in[1];
  const float* w_proj = (const float*)d_in[2];
  const float* b_proj = (const float*)d_in[3];
  const float* w_qk = (const float*)d_in[4];
  const float* w_v = (const float*)d_in[5];
  const float* w_out = (const float*)d_in[6];
  const float* b_out = (const float*)d_in[7];
  const float* rotations = (const float*)d_in[8];
  float* out = (float*)d_out;

  // Workspace layout (~227 MB, known to fit):
  const size_t szh = (size_t)BL * NPAD * DM;         // 17,301,504 elements
  const size_t szst = (size_t)BHTOT * NHASH * NPAD;  // 2,162,688 elements
  const size_t szL = (size_t)BHTOT * NPAD;           // 540,672 elements
  const size_t needed = 3 * szh * 4 + 2 * szst * 4 + szL * 4;
  if (ws_size < needed) return;  // diagnosable clean failure, not a fault

  float* qk = (float*)d_ws;
  float* v = qk + szh;
  float* att = v + szh;
  int* st = (int*)(att + szh);
  int* buckets = st + szst;
  float* ll = (float*)buckets;  // alias: buckets consumed by sort first
  float* L = (float*)(buckets + szst);

  (void)hipMemsetAsync(att, 0, szh * sizeof(float), stream);
  rot_bucket_kernel<<<dim3(NPAD / RTM, BL), dim3(384), 0, stream>>>(
      x, ste, w_proj, b_proj, w_qk, w_v, rotations, buckets, qk, v);
  sort_kernel<<<dim3(BHTOT, NHASH), dim3(384), 0, stream>>>(buckets, st);
  attn_lse_kernel<<<dim3(NCHUNK, BHTOT), dim3(512), 0, stream>>>(qk, st, ll);
  lcomb_kernel<<<dim3((BHTOT * NPAD + 255) / 256), dim3(256), 0, stream>>>(ll, L);
  attn_out_kernel<<<dim3(NCHUNK, BHTOT), dim3(512), 0, stream>>>(qk, v, st, L, att);
  outproj_kernel<<<dim3(21, BL), dim3(256), 0, stream>>>(att, w_out, b_out, out);
}

// Round 3
// 2314.847 us; speedup vs baseline: 1.3982x; 1.1224x over previous
//
#include <hip/hip_runtime.h>
#include <math.h>

// Problem constants (from setup_inputs)
#define BL 192      // b*l = 16*12
#define NREAL 325   // real sequence length
#define NPAD 352    // padded length (multiple of 2*bucket_size=32)
#define DM 256      // d_feat
#define DPOS 64     // d_pos
#define DIN 320     // d_feat + d_pos
#define NHEADS 8
#define EDIM 32     // DM / NHEADS
#define NHASH 4
#define BS 16       // bucket_size
#define NBUCK 22    // NPAD / BS
#define NCHUNK 88   // NHASH * NBUCK
#define BHTOT 1536  // BL * NHEADS
#define RROT 11     // n_buckets // 2
#define W2COLS 352  // NHEADS * NHASH * RROT
#define RTM 8       // row tile for qkv_rot_bucket kernel
#define HTM 16      // row tile for h kernel

// ---------------------------------------------------------------------------
// h = [x,ste]@w_proj + b_proj, serial-k fp32 FMA ascending (bit-exact vs the
// np reference chain).  A-operand addresses are block-uniform -> the compiler
// emits scalar loads (s_load) for them; B loads are lane-coalesced; no LDS.
// Pad rows (n >= NREAL) are written exactly 0.
__global__ __launch_bounds__(256) void h_kernel(
    const float* __restrict__ x, const float* __restrict__ ste,
    const float* __restrict__ wproj, const float* __restrict__ bproj,
    float* __restrict__ h) {
  int tile = blockIdx.x, bl = blockIdx.y;  // tile in [0, NPAD/HTM)
  int d = threadIdx.x;
  int n0 = tile * HTM;
  float acc[HTM];
#pragma unroll
  for (int m = 0; m < HTM; ++m) acc[m] = 0.f;
  if (n0 + HTM <= NREAL) {
    // fast path: all HTM rows valid
    const float* xb = x + (size_t)(bl * NREAL + n0) * DM;
    const float* sb = ste + (size_t)(bl * NREAL + n0) * DPOS;
    for (int k = 0; k < DM; k += 4) {
      float b0 = wproj[(k + 0) * DM + d];
      float b1 = wproj[(k + 1) * DM + d];
      float b2 = wproj[(k + 2) * DM + d];
      float b3 = wproj[(k + 3) * DM + d];
#pragma unroll
      for (int m = 0; m < HTM; ++m) {
        const float* xr = xb + (size_t)m * DM + k;
        acc[m] = fmaf(xr[0], b0, acc[m]);
        acc[m] = fmaf(xr[1], b1, acc[m]);
        acc[m] = fmaf(xr[2], b2, acc[m]);
        acc[m] = fmaf(xr[3], b3, acc[m]);
      }
    }
    for (int k = 0; k < DPOS; k += 4) {
      float b0 = wproj[(DM + k + 0) * DM + d];
      float b1 = wproj[(DM + k + 1) * DM + d];
      float b2 = wproj[(DM + k + 2) * DM + d];
      float b3 = wproj[(DM + k + 3) * DM + d];
#pragma unroll
      for (int m = 0; m < HTM; ++m) {
        const float* sr = sb + (size_t)m * DPOS + k;
        acc[m] = fmaf(sr[0], b0, acc[m]);
        acc[m] = fmaf(sr[1], b1, acc[m]);
        acc[m] = fmaf(sr[2], b2, acc[m]);
        acc[m] = fmaf(sr[3], b3, acc[m]);
      }
    }
  } else if (n0 < NREAL) {
    // partial tile (rows n0..NREAL-1 valid) — rare (192 blocks total)
#pragma unroll
    for (int m = 0; m < HTM; ++m) {
      if (n0 + m < NREAL) {
        const float* xr = x + (size_t)(bl * NREAL + n0 + m) * DM;
        const float* sr = ste + (size_t)(bl * NREAL + n0 + m) * DPOS;
        for (int k = 0; k < DM; ++k) acc[m] = fmaf(xr[k], wproj[k * DM + d], acc[m]);
        for (int k = 0; k < DPOS; ++k)
          acc[m] = fmaf(sr[k], wproj[(DM + k) * DM + d], acc[m]);
      }
    }
  }
  float bb = bproj[d];
#pragma unroll
  for (int m = 0; m < HTM; ++m) {
    int n = n0 + m;
    h[((size_t)(bl * NPAD + n)) * DM + d] = (n < NREAL) ? (acc[m] + bb) : 0.f;
  }
}

// ---------------------------------------------------------------------------
// qk = h@w_qk, v = h@w_v (serial-k fp32 FMA ascending, bit-exact), then
//   rot = einsum(qk, rotations)   fp32, separate mul+add (no fma)
//   bucket = argmax(concat(rot,-rot)), first-max tie rule.
// A-operand (h rows) read scalar-ly from global; all 256 lanes active.
__global__ __launch_bounds__(256) void qkv_rot_bucket_kernel(
    const float* __restrict__ h, const float* __restrict__ wqk,
    const float* __restrict__ wv, const float* __restrict__ rotations,
    int* __restrict__ buckets, float* __restrict__ qk_out,
    float* __restrict__ v_out) {
  int tile = blockIdx.x, bl = blockIdx.y;  // tile in [0,44)
  int tid = threadIdx.x;
  __shared__ float Qs[RTM][DM];     //  8,192 B
  __shared__ float Rs[RTM][W2COLS]; // 11,264 B
  int n0 = tile * RTM;
  const float* hb = h + (size_t)(bl * NPAD + n0) * DM;
  float aq[RTM], av[RTM];
#pragma unroll
  for (int m = 0; m < RTM; ++m) { aq[m] = 0.f; av[m] = 0.f; }
  for (int k = 0; k < DM; k += 4) {
    float q0 = wqk[(k + 0) * DM + tid];
    float q1 = wqk[(k + 1) * DM + tid];
    float q2 = wqk[(k + 2) * DM + tid];
    float q3 = wqk[(k + 3) * DM + tid];
    float w0 = wv[(k + 0) * DM + tid];
    float w1 = wv[(k + 1) * DM + tid];
    float w2 = wv[(k + 2) * DM + tid];
    float w3 = wv[(k + 3) * DM + tid];
#pragma unroll
    for (int m = 0; m < RTM; ++m) {
      const float* hr = hb + (size_t)m * DM + k;
      float a0 = hr[0], a1 = hr[1], a2 = hr[2], a3 = hr[3];
      aq[m] = fmaf(a0, q0, aq[m]);
      aq[m] = fmaf(a1, q1, aq[m]);
      aq[m] = fmaf(a2, q2, aq[m]);
      aq[m] = fmaf(a3, q3, aq[m]);
      av[m] = fmaf(a0, w0, av[m]);
      av[m] = fmaf(a1, w1, av[m]);
      av[m] = fmaf(a2, w2, av[m]);
      av[m] = fmaf(a3, w3, av[m]);
    }
  }
  {
    int head = tid >> 5, e = tid & 31;
    size_t bh = (size_t)(bl * NHEADS + head);
#pragma unroll
    for (int m = 0; m < RTM; ++m) {
      Qs[m][tid] = aq[m];
      int n = n0 + m;
      qk_out[(bh * NPAD + n) * EDIM + e] = aq[m];
      v_out[(bh * NPAD + n) * EDIM + e] = av[m];
    }
  }
  __syncthreads();
  for (int col = tid; col < W2COLS; col += 256) {
    // rot: serial-e fp32, separate mul and add (no fma)
    int head = col / 44;
    int hr = col - head * 44;
    int hs = hr / RROT;
    int r = hr - hs * RROT;
    float acc[RTM];
#pragma unroll
    for (int m = 0; m < RTM; ++m) acc[m] = 0.f;
    {
#pragma clang fp contract(off)
      for (int e = 0; e < EDIM; ++e) {
        float rr = rotations[(e * NHASH + hs) * RROT + r];
#pragma unroll
        for (int m = 0; m < RTM; ++m) {
          float p = Qs[m][head * EDIM + e] * rr;
          acc[m] = acc[m] + p;
        }
      }
    }
#pragma unroll
    for (int m = 0; m < RTM; ++m) Rs[m][col] = acc[m];
  }
  __syncthreads();
  {
    int m = tid >> 5;
    int rest = tid & 31;
    int head = rest >> 2;
    int hs = rest & 3;
    int cbase = head * 44 + hs * RROT;
    // argmax over concat([rot, -rot]), first-occurrence tie rule (strict >)
    float bestv = Rs[m][cbase];
    int best = 0;
    for (int r = 1; r < RROT; ++r) {
      float dv = Rs[m][cbase + r];
      if (dv > bestv) { bestv = dv; best = r; }
    }
    for (int r = 0; r < RROT; ++r) {
      float dv = -Rs[m][cbase + r];
      if (dv > bestv) { bestv = dv; best = RROT + r; }
    }
    int n = n0 + m;
    int bh = bl * NHEADS + head;
    buckets[((size_t)(bh * NHASH + hs)) * NPAD + n] = best;
  }
}

// ---------------------------------------------------------------------------
// Stable counting sort per (bh, hash): keys bucket*NPAD+n unique → exact argsort
__global__ __launch_bounds__(384) void sort_kernel(const int* __restrict__ buckets,
                                                   int* __restrict__ st) {
  int bh = blockIdx.x, hs = blockIdx.y;
  int n = threadIdx.x;
  __shared__ int buck[NPAD];
  const int* brow = buckets + ((size_t)(bh * NHASH + hs)) * NPAD;
  if (n < NPAD) buck[n] = brow[n];
  __syncthreads();
  if (n < NPAD) {
    int b = buck[n];
    int dest = 0;
    for (int m2 = 0; m2 < NPAD; ++m2) {
      int bm = buck[m2];
      dest += (int)((bm < b) | ((bm == b) & (m2 < n)));
    }
    st[((size_t)(bh * NHASH + hs)) * NPAD + dest] = n;
  }
}

// ---------------------------------------------------------------------------
// Pass 1: per chunk, fp64 dots → per-(bh,hash,pos) lse (stored fp32).
__global__ __launch_bounds__(512) void attn_lse_kernel(
    const float* __restrict__ qk, const int* __restrict__ st,
    float* __restrict__ ll) {
  int c = blockIdx.x, bh = blockIdx.y;
  int t = threadIdx.x;
  int i = t >> 5, j = t & 31;  // query i (0..15), key j (0..31)
  __shared__ float qs[16][EDIM];
  __shared__ float ks[32][EDIM + 1];
  __shared__ int qpos[16];
  __shared__ int kpos[32];
  __shared__ double rnorm[32];
  const int* strow = st + (size_t)bh * (NHASH * NPAD);
  int pc = (c + NCHUNK - 1) % NCHUNK;
  if (t < 16) {
    qpos[t] = strow[c * BS + t];
  } else if (t < 48) {
    int jj = t - 16;
    kpos[jj] = (jj < BS) ? strow[c * BS + jj] : strow[pc * BS + (jj - BS)];
  }
  __syncthreads();
  const float* qkb = qk + (size_t)bh * NPAD * EDIM;
  qs[i][j] = qkb[qpos[i] * EDIM + j];
#pragma unroll
  for (int rep = 0; rep < 2; ++rep) {
    int lin = t + rep * 512;
    int r = lin >> 5, cc = lin & 31;
    ks[r][cc] = qkb[kpos[r] * EDIM + cc];
  }
  __syncthreads();
  if (t < 32) {
    double s = 0.0;
#pragma unroll
    for (int e = 0; e < EDIM; ++e) { double kv = (double)ks[t][e]; s += kv * kv; }
    rnorm[t] = 1.0 / fmax(sqrt(s), 1e-12);
  }
  __syncthreads();
  double dot = 0.0;
#pragma unroll
  for (int e = 0; e < EDIM; ++e) dot += (double)qs[i][e] * (double)ks[j][e];
  dot *= rnorm[j] * 0.17677669529663688;  // E^-0.5
  if (qpos[i] == kpos[j]) dot = -50000.0;
  double mx = dot;
#pragma unroll
  for (int off = 16; off > 0; off >>= 1) mx = fmax(mx, __shfl_xor(mx, off, 32));
  double ex = exp(dot - mx);
  double sm = ex;
#pragma unroll
  for (int off = 16; off > 0; off >>= 1) sm += __shfl_xor(sm, off, 32);
  if (j == 0) {
    int hs = c / NBUCK;
    ll[((size_t)(bh * NHASH + hs)) * NPAD + qpos[i]] = (float)(mx + log(sm));
  }
}

// ---------------------------------------------------------------------------
// L[bh][n] = logsumexp over the 4 hash rounds' lse (fp64 math, fp32 store)
__global__ __launch_bounds__(256) void lcomb_kernel(const float* __restrict__ ll,
                                                    float* __restrict__ L) {
  int gid = blockIdx.x * 256 + threadIdx.x;
  if (gid >= BHTOT * NPAD) return;
  int n = gid % NPAD, bh = gid / NPAD;
  double l0 = (double)ll[((size_t)(bh * NHASH + 0)) * NPAD + n];
  double l1 = (double)ll[((size_t)(bh * NHASH + 1)) * NPAD + n];
  double l2 = (double)ll[((size_t)(bh * NHASH + 2)) * NPAD + n];
  double l3 = (double)ll[((size_t)(bh * NHASH + 3)) * NPAD + n];
  double m = fmax(fmax(l0, l1), fmax(l2, l3));
  double s = exp(l0 - m) + exp(l1 - m) + exp(l2 - m) + exp(l3 - m);
  L[gid] = (float)(m + log(s));
}

// ---------------------------------------------------------------------------
// Pass 2: fp64 dots, p = exp(dot - L[pos]) (hash-combine folded into the
// exponent), acc = p @ V in fp64, fp32 atomicAdd into att[bl][n][head*32+e].
__global__ __launch_bounds__(512) void attn_out_kernel(
    const float* __restrict__ qk, const float* __restrict__ v,
    const int* __restrict__ st, const float* __restrict__ L,
    float* __restrict__ att) {
  int c = blockIdx.x, bh = blockIdx.y;
  int t = threadIdx.x;
  int i = t >> 5, j = t & 31;
  __shared__ float qs[16][EDIM];
  __shared__ float ks[32][EDIM + 1];
  __shared__ float vs[32][EDIM + 1];
  __shared__ double ps[16][32];
  __shared__ int qpos[16];
  __shared__ int kpos[32];
  __shared__ double rnorm[32];
  const int* strow = st + (size_t)bh * (NHASH * NPAD);
  int pc = (c + NCHUNK - 1) % NCHUNK;
  if (t < 16) {
    qpos[t] = strow[c * BS + t];
  } else if (t < 48) {
    int jj = t - 16;
    kpos[jj] = (jj < BS) ? strow[c * BS + jj] : strow[pc * BS + (jj - BS)];
  }
  __syncthreads();
  const float* qkb = qk + (size_t)bh * NPAD * EDIM;
  const float* vb = v + (size_t)bh * NPAD * EDIM;
  qs[i][j] = qkb[qpos[i] * EDIM + j];
#pragma unroll
  for (int rep = 0; rep < 2; ++rep) {
    int lin = t + rep * 512;
    int r = lin >> 5, cc = lin & 31;
    ks[r][cc] = qkb[kpos[r] * EDIM + cc];
    vs[r][cc] = vb[kpos[r] * EDIM + cc];
  }
  __syncthreads();
  if (t < 32) {
    double s = 0.0;
#pragma unroll
    for (int e = 0; e < EDIM; ++e) { double kv = (double)ks[t][e]; s += kv * kv; }
    rnorm[t] = 1.0 / fmax(sqrt(s), 1e-12);
  }
  __syncthreads();
  double dot = 0.0;
#pragma unroll
  for (int e = 0; e < EDIM; ++e) dot += (double)qs[i][e] * (double)ks[j][e];
  dot *= rnorm[j] * 0.17677669529663688;
  if (qpos[i] == kpos[j]) dot = -50000.0;
  ps[i][j] = exp(dot - (double)L[(size_t)bh * NPAD + qpos[i]]);
  __syncthreads();
  double acc = 0.0;
#pragma unroll
  for (int jj = 0; jj < 32; ++jj) acc += ps[i][jj] * (double)vs[jj][j];
  int head = bh & 7, bl = bh >> 3;
  int qp = qpos[i];
  atomicAdd(&att[((size_t)(bl * NPAD + qp)) * DM + head * EDIM + j], (float)acc);
}

// ---------------------------------------------------------------------------
// out = att @ w_out + b_out (fp64 accumulate), first NREAL rows only
__global__ __launch_bounds__(256) void outproj_kernel(
    const float* __restrict__ att, const float* __restrict__ w,
    const float* __restrict__ bias, float* __restrict__ out) {
  int tile = blockIdx.x, bl = blockIdx.y;
  int d = threadIdx.x;
  __shared__ float As[16][DM];
  int n0 = tile * 16;
  for (int idx = threadIdx.x; idx < 16 * DM; idx += 256) {
    int m = idx >> 8, k = idx & 255;
    int n = n0 + m;
    As[m][k] = (n < NREAL) ? att[((size_t)(bl * NPAD + n)) * DM + k] : 0.f;
  }
  __syncthreads();
  double acc[16];
#pragma unroll
  for (int m = 0; m < 16; ++m) acc[m] = 0.0;
  for (int k = 0; k < DM; ++k) {
    double b = (double)w[k * DM + d];
#pragma unroll
    for (int m = 0; m < 16; ++m) acc[m] += (double)As[m][k] * b;
  }
  double bb = (double)bias[d];
  for (int m = 0; m < 16; ++m) {
    int n = n0 + m;
    if (n < NREAL) out[((size_t)(bl * NREAL + n)) * DM + d] = (float)(acc[m] + bb);
  }
}

// ---------------------------------------------------------------------------
extern "C" void kernel_launch(void* const* d_in, const int* in_sizes, int n_in,
                              void* d_out, int out_size, void* d_ws, size_t ws_size,
                              hipStream_t stream) {
  (void)in_sizes; (void)n_in; (void)out_size;
  const float* x = (const float*)d_in[0];
  const float* ste = (const float*)d_in[1];
  const float* w_proj = (const float*)d_in[2];
  const float* b_proj = (const float*)d_in[3];
  const float* w_qk = (const float*)d_in[4];
  const float* w_v = (const float*)d_in[5];
  const float* w_out = (const float*)d_in[6];
  const float* b_out = (const float*)d_in[7];
  const float* rotations = (const float*)d_in[8];
  float* out = (float*)d_out;

  // Workspace layout (~227 MB, known to fit):
  const size_t szh = (size_t)BL * NPAD * DM;         // 17,301,504 elements
  const size_t szst = (size_t)BHTOT * NHASH * NPAD;  // 2,162,688 elements
  const size_t szL = (size_t)BHTOT * NPAD;           // 540,672 elements
  const size_t needed = 3 * szh * 4 + 2 * szst * 4 + szL * 4;
  if (ws_size < needed) return;  // diagnosable clean failure, not a fault

  float* qk = (float*)d_ws;
  float* v = qk + szh;
  float* att = v + szh;        // doubles as the h buffer before attn_out
  float* h = att;              // alias: h consumed by qkv kernel, then att reused
  int* st = (int*)(att + szh);
  int* buckets = st + szst;
  float* ll = (float*)buckets;  // alias: buckets consumed by sort first
  float* L = (float*)(buckets + szst);

  h_kernel<<<dim3(NPAD / HTM, BL), dim3(256), 0, stream>>>(
      x, ste, w_proj, b_proj, h);
  qkv_rot_bucket_kernel<<<dim3(NPAD / RTM, BL), dim3(256), 0, stream>>>(
      h, w_qk, w_v, rotations, buckets, qk, v);
  // att aliases h; h is fully consumed above, so zero it now for attn_out.
  (void)hipMemsetAsync(att, 0, szh * sizeof(float), stream);
  sort_kernel<<<dim3(BHTOT, NHASH), dim3(384), 0, stream>>>(buckets, st);
  attn_lse_kernel<<<dim3(NCHUNK, BHTOT), dim3(512), 0, stream>>>(qk, st, ll);
  lcomb_kernel<<<dim3((BHTOT * NPAD + 255) / 256), dim3(256), 0, stream>>>(ll, L);
  attn_out_kernel<<<dim3(NCHUNK, BHTOT), dim3(512), 0, stream>>>(qk, v, st, L, att);
  outproj_kernel<<<dim3(21, BL), dim3(256), 0, stream>>>(att, w_out, b_out, out);
}

// Round 4
// 1806.786 us; speedup vs baseline: 1.7914x; 1.2812x over previous
//
#include <hip/hip_runtime.h>
#include <math.h>

// Problem constants (from setup_inputs)
#define BL 192      // b*l = 16*12
#define NREAL 325   // real sequence length
#define NPAD 352    // padded length (multiple of 2*bucket_size=32)
#define DM 256      // d_feat
#define DPOS 64     // d_pos
#define DIN 320     // d_feat + d_pos
#define NHEADS 8
#define EDIM 32     // DM / NHEADS
#define NHASH 4
#define BS 16       // bucket_size
#define NBUCK 22    // NPAD / BS
#define NCHUNK 88   // NHASH * NBUCK
#define BHTOT 1536  // BL * NHEADS
#define RROT 11     // n_buckets // 2
#define W2COLS 352  // NHEADS * NHASH * RROT
#define RTM 8       // row tile for qkv_rot_bucket kernel
#define HTM 16      // row tile for h kernel / outproj

// ---------------------------------------------------------------------------
// h = [x,ste]@w_proj + b_proj, serial-k fp32 FMA ascending (bit-exact vs the
// np reference chain).  A-operand addresses are block-uniform -> scalar loads;
// B loads are lane-coalesced; no LDS.  Pad rows (n >= NREAL) exactly 0.
__global__ __launch_bounds__(256) void h_kernel(
    const float* __restrict__ x, const float* __restrict__ ste,
    const float* __restrict__ wproj, const float* __restrict__ bproj,
    float* __restrict__ h) {
  int tile = blockIdx.x, bl = blockIdx.y;  // tile in [0, NPAD/HTM)
  int d = threadIdx.x;
  int n0 = tile * HTM;
  float acc[HTM];
#pragma unroll
  for (int m = 0; m < HTM; ++m) acc[m] = 0.f;
  if (n0 + HTM <= NREAL) {
    // fast path: all HTM rows valid
    const float* xb = x + (size_t)(bl * NREAL + n0) * DM;
    const float* sb = ste + (size_t)(bl * NREAL + n0) * DPOS;
    for (int k = 0; k < DM; k += 4) {
      float b0 = wproj[(k + 0) * DM + d];
      float b1 = wproj[(k + 1) * DM + d];
      float b2 = wproj[(k + 2) * DM + d];
      float b3 = wproj[(k + 3) * DM + d];
#pragma unroll
      for (int m = 0; m < HTM; ++m) {
        const float* xr = xb + (size_t)m * DM + k;
        acc[m] = fmaf(xr[0], b0, acc[m]);
        acc[m] = fmaf(xr[1], b1, acc[m]);
        acc[m] = fmaf(xr[2], b2, acc[m]);
        acc[m] = fmaf(xr[3], b3, acc[m]);
      }
    }
    for (int k = 0; k < DPOS; k += 4) {
      float b0 = wproj[(DM + k + 0) * DM + d];
      float b1 = wproj[(DM + k + 1) * DM + d];
      float b2 = wproj[(DM + k + 2) * DM + d];
      float b3 = wproj[(DM + k + 3) * DM + d];
#pragma unroll
      for (int m = 0; m < HTM; ++m) {
        const float* sr = sb + (size_t)m * DPOS + k;
        acc[m] = fmaf(sr[0], b0, acc[m]);
        acc[m] = fmaf(sr[1], b1, acc[m]);
        acc[m] = fmaf(sr[2], b2, acc[m]);
        acc[m] = fmaf(sr[3], b3, acc[m]);
      }
    }
  } else if (n0 < NREAL) {
    // partial tile (rows n0..NREAL-1 valid) — rare (192 blocks total)
#pragma unroll
    for (int m = 0; m < HTM; ++m) {
      if (n0 + m < NREAL) {
        const float* xr = x + (size_t)(bl * NREAL + n0 + m) * DM;
        const float* sr = ste + (size_t)(bl * NREAL + n0 + m) * DPOS;
        for (int k = 0; k < DM; ++k) acc[m] = fmaf(xr[k], wproj[k * DM + d], acc[m]);
        for (int k = 0; k < DPOS; ++k)
          acc[m] = fmaf(sr[k], wproj[(DM + k) * DM + d], acc[m]);
      }
    }
  }
  float bb = bproj[d];
#pragma unroll
  for (int m = 0; m < HTM; ++m) {
    int n = n0 + m;
    h[((size_t)(bl * NPAD + n)) * DM + d] = (n < NREAL) ? (acc[m] + bb) : 0.f;
  }
}

// ---------------------------------------------------------------------------
// qk = h@w_qk, v = h@w_v (serial-k fp32 FMA ascending, bit-exact), then
//   rot = einsum(qk, rotations)   fp32, separate mul+add (no fma)
//   bucket = argmax(concat(rot,-rot)), first-max tie rule.
__global__ __launch_bounds__(256) void qkv_rot_bucket_kernel(
    const float* __restrict__ h, const float* __restrict__ wqk,
    const float* __restrict__ wv, const float* __restrict__ rotations,
    int* __restrict__ buckets, float* __restrict__ qk_out,
    float* __restrict__ v_out) {
  int tile = blockIdx.x, bl = blockIdx.y;  // tile in [0,44)
  int tid = threadIdx.x;
  __shared__ float Qs[RTM][DM];     //  8,192 B
  __shared__ float Rs[RTM][W2COLS]; // 11,264 B
  int n0 = tile * RTM;
  const float* hb = h + (size_t)(bl * NPAD + n0) * DM;
  float aq[RTM], av[RTM];
#pragma unroll
  for (int m = 0; m < RTM; ++m) { aq[m] = 0.f; av[m] = 0.f; }
  for (int k = 0; k < DM; k += 4) {
    float q0 = wqk[(k + 0) * DM + tid];
    float q1 = wqk[(k + 1) * DM + tid];
    float q2 = wqk[(k + 2) * DM + tid];
    float q3 = wqk[(k + 3) * DM + tid];
    float w0 = wv[(k + 0) * DM + tid];
    float w1 = wv[(k + 1) * DM + tid];
    float w2 = wv[(k + 2) * DM + tid];
    float w3 = wv[(k + 3) * DM + tid];
#pragma unroll
    for (int m = 0; m < RTM; ++m) {
      const float* hr = hb + (size_t)m * DM + k;
      float a0 = hr[0], a1 = hr[1], a2 = hr[2], a3 = hr[3];
      aq[m] = fmaf(a0, q0, aq[m]);
      aq[m] = fmaf(a1, q1, aq[m]);
      aq[m] = fmaf(a2, q2, aq[m]);
      aq[m] = fmaf(a3, q3, aq[m]);
      av[m] = fmaf(a0, w0, av[m]);
      av[m] = fmaf(a1, w1, av[m]);
      av[m] = fmaf(a2, w2, av[m]);
      av[m] = fmaf(a3, w3, av[m]);
    }
  }
  {
    int head = tid >> 5, e = tid & 31;
    size_t bh = (size_t)(bl * NHEADS + head);
#pragma unroll
    for (int m = 0; m < RTM; ++m) {
      Qs[m][tid] = aq[m];
      int n = n0 + m;
      qk_out[(bh * NPAD + n) * EDIM + e] = aq[m];
      v_out[(bh * NPAD + n) * EDIM + e] = av[m];
    }
  }
  __syncthreads();
  for (int col = tid; col < W2COLS; col += 256) {
    // rot: serial-e fp32, separate mul and add (no fma)
    int head = col / 44;
    int hr = col - head * 44;
    int hs = hr / RROT;
    int r = hr - hs * RROT;
    float acc[RTM];
#pragma unroll
    for (int m = 0; m < RTM; ++m) acc[m] = 0.f;
    {
#pragma clang fp contract(off)
      for (int e = 0; e < EDIM; ++e) {
        float rr = rotations[(e * NHASH + hs) * RROT + r];
#pragma unroll
        for (int m = 0; m < RTM; ++m) {
          float p = Qs[m][head * EDIM + e] * rr;
          acc[m] = acc[m] + p;
        }
      }
    }
#pragma unroll
    for (int m = 0; m < RTM; ++m) Rs[m][col] = acc[m];
  }
  __syncthreads();
  {
    int m = tid >> 5;
    int rest = tid & 31;
    int head = rest >> 2;
    int hs = rest & 3;
    int cbase = head * 44 + hs * RROT;
    // argmax over concat([rot, -rot]), first-occurrence tie rule (strict >)
    float bestv = Rs[m][cbase];
    int best = 0;
    for (int r = 1; r < RROT; ++r) {
      float dv = Rs[m][cbase + r];
      if (dv > bestv) { bestv = dv; best = r; }
    }
    for (int r = 0; r < RROT; ++r) {
      float dv = -Rs[m][cbase + r];
      if (dv > bestv) { bestv = dv; best = RROT + r; }
    }
    int n = n0 + m;
    int bh = bl * NHEADS + head;
    buckets[((size_t)(bh * NHASH + hs)) * NPAD + n] = best;
  }
}

// ---------------------------------------------------------------------------
// Stable counting sort per (bh, hash): keys bucket*NPAD+n unique → exact argsort
__global__ __launch_bounds__(384) void sort_kernel(const int* __restrict__ buckets,
                                                   int* __restrict__ st) {
  int bh = blockIdx.x, hs = blockIdx.y;
  int n = threadIdx.x;
  __shared__ int buck[NPAD];
  const int* brow = buckets + ((size_t)(bh * NHASH + hs)) * NPAD;
  if (n < NPAD) buck[n] = brow[n];
  __syncthreads();
  if (n < NPAD) {
    int b = buck[n];
    int dest = 0;
    for (int m2 = 0; m2 < NPAD; ++m2) {
      int bm = buck[m2];
      dest += (int)((bm < b) | ((bm == b) & (m2 < n)));
    }
    st[((size_t)(bh * NHASH + hs)) * NPAD + dest] = n;
  }
}

// ---------------------------------------------------------------------------
// Pass 1: per chunk, fp32 dots → per-(bh,hash,pos) lse.
__global__ __launch_bounds__(512) void attn_lse_kernel(
    const float* __restrict__ qk, const int* __restrict__ st,
    float* __restrict__ ll) {
  int c = blockIdx.x, bh = blockIdx.y;
  int t = threadIdx.x;
  int i = t >> 5, j = t & 31;  // query i (0..15), key j (0..31)
  __shared__ float qs[16][EDIM];
  __shared__ float ks[32][EDIM + 1];
  __shared__ int qpos[16];
  __shared__ int kpos[32];
  __shared__ float rnorm[32];
  const int* strow = st + (size_t)bh * (NHASH * NPAD);
  int pc = (c + NCHUNK - 1) % NCHUNK;
  if (t < 16) {
    qpos[t] = strow[c * BS + t];
  } else if (t < 48) {
    int jj = t - 16;
    kpos[jj] = (jj < BS) ? strow[c * BS + jj] : strow[pc * BS + (jj - BS)];
  }
  __syncthreads();
  const float* qkb = qk + (size_t)bh * NPAD * EDIM;
  qs[i][j] = qkb[qpos[i] * EDIM + j];
#pragma unroll
  for (int rep = 0; rep < 2; ++rep) {
    int lin = t + rep * 512;
    int r = lin >> 5, cc = lin & 31;
    ks[r][cc] = qkb[kpos[r] * EDIM + cc];
  }
  __syncthreads();
  if (t < 32) {
    float s = 0.f;
#pragma unroll
    for (int e = 0; e < EDIM; ++e) { float kv = ks[t][e]; s = fmaf(kv, kv, s); }
    rnorm[t] = 1.0f / fmaxf(sqrtf(s), 1e-12f);
  }
  __syncthreads();
  float dot = 0.f;
#pragma unroll
  for (int e = 0; e < EDIM; ++e) dot = fmaf(qs[i][e], ks[j][e], dot);
  dot *= rnorm[j] * 0.17677669529663688f;  // E^-0.5
  if (qpos[i] == kpos[j]) dot = -50000.0f;
  float mx = dot;
#pragma unroll
  for (int off = 16; off > 0; off >>= 1) mx = fmaxf(mx, __shfl_xor(mx, off, 32));
  float ex = expf(dot - mx);
  float sm = ex;
#pragma unroll
  for (int off = 16; off > 0; off >>= 1) sm += __shfl_xor(sm, off, 32);
  if (j == 0) {
    int hs = c / NBUCK;
    ll[((size_t)(bh * NHASH + hs)) * NPAD + qpos[i]] = mx + logf(sm);
  }
}

// ---------------------------------------------------------------------------
// L[bh][n] = logsumexp over the 4 hash rounds' lse (fp32)
__global__ __launch_bounds__(256) void lcomb_kernel(const float* __restrict__ ll,
                                                    float* __restrict__ L) {
  int gid = blockIdx.x * 256 + threadIdx.x;
  if (gid >= BHTOT * NPAD) return;
  int n = gid % NPAD, bh = gid / NPAD;
  float l0 = ll[((size_t)(bh * NHASH + 0)) * NPAD + n];
  float l1 = ll[((size_t)(bh * NHASH + 1)) * NPAD + n];
  float l2 = ll[((size_t)(bh * NHASH + 2)) * NPAD + n];
  float l3 = ll[((size_t)(bh * NHASH + 3)) * NPAD + n];
  float m = fmaxf(fmaxf(l0, l1), fmaxf(l2, l3));
  float s = expf(l0 - m) + expf(l1 - m) + expf(l2 - m) + expf(l3 - m);
  L[gid] = m + logf(s);
}

// ---------------------------------------------------------------------------
// Pass 2: fp32 dots, p = exp(dot - L[pos]) (hash-combine folded into the
// exponent), acc = p @ V in fp32, fp32 atomicAdd into att[bl][n][head*32+e].
__global__ __launch_bounds__(512) void attn_out_kernel(
    const float* __restrict__ qk, const float* __restrict__ v,
    const int* __restrict__ st, const float* __restrict__ L,
    float* __restrict__ att) {
  int c = blockIdx.x, bh = blockIdx.y;
  int t = threadIdx.x;
  int i = t >> 5, j = t & 31;
  __shared__ float qs[16][EDIM];
  __shared__ float ks[32][EDIM + 1];
  __shared__ float vs[32][EDIM + 1];
  __shared__ float ps[16][32];
  __shared__ int qpos[16];
  __shared__ int kpos[32];
  __shared__ float rnorm[32];
  const int* strow = st + (size_t)bh * (NHASH * NPAD);
  int pc = (c + NCHUNK - 1) % NCHUNK;
  if (t < 16) {
    qpos[t] = strow[c * BS + t];
  } else if (t < 48) {
    int jj = t - 16;
    kpos[jj] = (jj < BS) ? strow[c * BS + jj] : strow[pc * BS + (jj - BS)];
  }
  __syncthreads();
  const float* qkb = qk + (size_t)bh * NPAD * EDIM;
  const float* vb = v + (size_t)bh * NPAD * EDIM;
  qs[i][j] = qkb[qpos[i] * EDIM + j];
#pragma unroll
  for (int rep = 0; rep < 2; ++rep) {
    int lin = t + rep * 512;
    int r = lin >> 5, cc = lin & 31;
    ks[r][cc] = qkb[kpos[r] * EDIM + cc];
    vs[r][cc] = vb[kpos[r] * EDIM + cc];
  }
  __syncthreads();
  if (t < 32) {
    float s = 0.f;
#pragma unroll
    for (int e = 0; e < EDIM; ++e) { float kv = ks[t][e]; s = fmaf(kv, kv, s); }
    rnorm[t] = 1.0f / fmaxf(sqrtf(s), 1e-12f);
  }
  __syncthreads();
  float dot = 0.f;
#pragma unroll
  for (int e = 0; e < EDIM; ++e) dot = fmaf(qs[i][e], ks[j][e], dot);
  dot *= rnorm[j] * 0.17677669529663688f;
  if (qpos[i] == kpos[j]) dot = -50000.0f;
  ps[i][j] = expf(dot - L[(size_t)bh * NPAD + qpos[i]]);
  __syncthreads();
  float acc = 0.f;
#pragma unroll
  for (int jj = 0; jj < 32; ++jj) acc = fmaf(ps[i][jj], vs[jj][j], acc);
  int head = bh & 7, bl = bh >> 3;
  int qp = qpos[i];
  atomicAdd(&att[((size_t)(bl * NPAD + qp)) * DM + head * EDIM + j], acc);
}

// ---------------------------------------------------------------------------
// out = att @ w_out + b_out (fp32 serial-k, scalar A loads), real rows only
__global__ __launch_bounds__(256) void outproj_kernel(
    const float* __restrict__ att, const float* __restrict__ w,
    const float* __restrict__ bias, float* __restrict__ out) {
  int tile = blockIdx.x, bl = blockIdx.y;
  int d = threadIdx.x;
  int n0 = tile * HTM;
  float acc[HTM];
#pragma unroll
  for (int m = 0; m < HTM; ++m) acc[m] = 0.f;
  if (n0 + HTM <= NREAL) {
    const float* ab = att + (size_t)(bl * NPAD + n0) * DM;
    for (int k = 0; k < DM; k += 4) {
      float b0 = w[(k + 0) * DM + d];
      float b1 = w[(k + 1) * DM + d];
      float b2 = w[(k + 2) * DM + d];
      float b3 = w[(k + 3) * DM + d];
#pragma unroll
      for (int m = 0; m < HTM; ++m) {
        const float* ar = ab + (size_t)m * DM + k;
        acc[m] = fmaf(ar[0], b0, acc[m]);
        acc[m] = fmaf(ar[1], b1, acc[m]);
        acc[m] = fmaf(ar[2], b2, acc[m]);
        acc[m] = fmaf(ar[3], b3, acc[m]);
      }
    }
  } else if (n0 < NREAL) {
#pragma unroll
    for (int m = 0; m < HTM; ++m) {
      if (n0 + m < NREAL) {
        const float* ar = att + (size_t)(bl * NPAD + n0 + m) * DM;
        for (int k = 0; k < DM; ++k) acc[m] = fmaf(ar[k], w[k * DM + d], acc[m]);
      }
    }
  } else {
    return;
  }
  float bb = bias[d];
#pragma unroll
  for (int m = 0; m < HTM; ++m) {
    int n = n0 + m;
    if (n < NREAL) out[((size_t)(bl * NREAL + n)) * DM + d] = acc[m] + bb;
  }
}

// ---------------------------------------------------------------------------
extern "C" void kernel_launch(void* const* d_in, const int* in_sizes, int n_in,
                              void* d_out, int out_size, void* d_ws, size_t ws_size,
                              hipStream_t stream) {
  (void)in_sizes; (void)n_in; (void)out_size;
  const float* x = (const float*)d_in[0];
  const float* ste = (const float*)d_in[1];
  const float* w_proj = (const float*)d_in[2];
  const float* b_proj = (const float*)d_in[3];
  const float* w_qk = (const float*)d_in[4];
  const float* w_v = (const float*)d_in[5];
  const float* w_out = (const float*)d_in[6];
  const float* b_out = (const float*)d_in[7];
  const float* rotations = (const float*)d_in[8];
  float* out = (float*)d_out;

  // Workspace layout (~227 MB, known to fit):
  const size_t szh = (size_t)BL * NPAD * DM;         // 17,301,504 elements
  const size_t szst = (size_t)BHTOT * NHASH * NPAD;  // 2,162,688 elements
  const size_t szL = (size_t)BHTOT * NPAD;           // 540,672 elements
  const size_t needed = 3 * szh * 4 + 2 * szst * 4 + szL * 4;
  if (ws_size < needed) return;  // diagnosable clean failure, not a fault

  float* qk = (float*)d_ws;
  float* v = qk + szh;
  float* att = v + szh;        // doubles as the h buffer before attn_out
  float* h = att;              // alias: h consumed by qkv kernel, then att reused
  int* st = (int*)(att + szh);
  int* buckets = st + szst;
  float* ll = (float*)buckets;  // alias: buckets consumed by sort first
  float* L = (float*)(buckets + szst);

  h_kernel<<<dim3(NPAD / HTM, BL), dim3(256), 0, stream>>>(
      x, ste, w_proj, b_proj, h);
  qkv_rot_bucket_kernel<<<dim3(NPAD / RTM, BL), dim3(256), 0, stream>>>(
      h, w_qk, w_v, rotations, buckets, qk, v);
  // att aliases h; h is fully consumed above, so zero it now for attn_out.
  (void)hipMemsetAsync(att, 0, szh * sizeof(float), stream);
  sort_kernel<<<dim3(BHTOT, NHASH), dim3(384), 0, stream>>>(buckets, st);
  attn_lse_kernel<<<dim3(NCHUNK, BHTOT), dim3(512), 0, stream>>>(qk, st, ll);
  lcomb_kernel<<<dim3((BHTOT * NPAD + 255) / 256), dim3(256), 0, stream>>>(ll, L);
  attn_out_kernel<<<dim3(NCHUNK, BHTOT), dim3(512), 0, stream>>>(qk, v, st, L, att);
  outproj_kernel<<<dim3(21, BL), dim3(256), 0, stream>>>(att, w_out, b_out, out);
}